// Round 1
// baseline (213.100 us; speedup 1.0000x reference)
//
#include <hip/hip_runtime.h>
#include <hip/hip_bf16.h>

#define VOCAB 100
#define EMBD 128
#define SDIM 16
#define HID 32
#define NLAYER 5
#define GSEG 8192

// K1: grid 50 x 128 threads. Block b handles vocab rows v0=2b, v0+1.
// Phase 1 (threads 0..63, two 32-lane groups): compute scale[v] through the
// 5-layer mask MLP. Phase 2 (all 128): A[v][j] = scale[v] * dot(emb[v], pw1[:,j]).
__global__ void k_table(const float* __restrict__ emb,
                        const float* __restrict__ w1, const float* __restrict__ b1,
                        const float* __restrict__ w2, const float* __restrict__ b2,
                        const float* __restrict__ pw1,
                        float* __restrict__ A) {
    __shared__ float s_scale[2];
    int t = threadIdx.x;
    int v0 = blockIdx.x * 2;
    if (t < 64) {
        int vv = v0 + (t >> 5);   // which of the two vocab rows
        int jj = t & 31;          // hidden unit 0..31
        float e[SDIM];
        #pragma unroll
        for (int k = 0; k < SDIM; ++k) e[k] = emb[vv * EMBD + k];
        float scale = 1.0f;
        for (int l = 0; l < NLAYER; ++l) {
            // z_j = relu(scale * dot(e, w1[l,:,j]) + b1[l,j])
            float d = 0.f;
            #pragma unroll
            for (int k = 0; k < SDIM; ++k)
                d = fmaf(e[k], w1[l * (SDIM * HID) + k * HID + jj], d);
            float z = fmaf(scale, d, b1[l * HID + jj]);
            z = fmaxf(z, 0.f);
            float p = z * w2[l * HID + jj];
            #pragma unroll
            for (int off = 16; off; off >>= 1)
                p += __shfl_xor(p, off, 32);        // butterfly: all 32 lanes get sum
            float logit = p + b2[l];
            float m = 1.f / (1.f + expf(-logit));
            if (!(m > 0.5f)) scale *= (1.f - m);    // m>0.5 => h unchanged
        }
        if (jj == 0) s_scale[t >> 5] = scale;
    }
    __syncthreads();
    {
        int vl = t >> 6;          // 0..1
        int j  = t & 63;
        int v  = v0 + vl;
        float sc = s_scale[vl];
        float acc = 0.f;
        #pragma unroll 4
        for (int d = 0; d < EMBD; ++d)
            acc = fmaf(emb[v * EMBD + d], pw1[d * 64 + j], acc);
        A[v * 64 + j] = sc * acc;
    }
}

// K2: segment offsets from sorted batch. seg[g] = first index a with batch[a] >= g.
__global__ void k_seg(const int* __restrict__ batch, int n, int* __restrict__ seg) {
    int a = blockIdx.x * blockDim.x + threadIdx.x;
    if (a >= n) return;
    if (a == 0) {
        int b0 = batch[0];
        for (int g = 0; g <= b0; ++g) seg[g] = 0;
    } else {
        int bp = batch[a - 1], bc = batch[a];
        if (bp != bc)
            for (int g = bp + 1; g <= bc; ++g) seg[g] = a;
    }
    if (a == n - 1) {
        int bl = batch[n - 1];
        for (int g = bl + 1; g <= GSEG; ++g) seg[g] = n;
    }
}

// K3: one 64-thread block per segment. Histogram its atoms into LDS, then
// hidden_j = pb1[j] + sum_v cnt[v]*A[v][j]; out = relu(hidden) . pw2 + pb2.
__global__ void __launch_bounds__(64) k_main(const int* __restrict__ atoms,
                                             const int* __restrict__ seg,
                                             const float* __restrict__ A,
                                             const float* __restrict__ pb1,
                                             const float* __restrict__ pw2,
                                             const float* __restrict__ pb2,
                                             float* __restrict__ out) {
    __shared__ int s_cnt[VOCAB];
    int t = threadIdx.x;
    int g = blockIdx.x;
    for (int i = t; i < VOCAB; i += 64) s_cnt[i] = 0;
    __syncthreads();
    int start = seg[g], end = seg[g + 1];
    for (int a = start + t; a < end; a += 64)
        atomicAdd(&s_cnt[atoms[a]], 1);
    __syncthreads();
    float h = pb1[t];
    #pragma unroll 4
    for (int v = 0; v < VOCAB; ++v)
        h = fmaf((float)s_cnt[v], A[v * 64 + t], h);   // s_cnt: LDS broadcast; A: coalesced, L1-hot
    float part = fmaxf(h, 0.f) * pw2[t];
    #pragma unroll
    for (int off = 32; off; off >>= 1)
        part += __shfl_down(part, off, 64);
    if (t == 0) out[g] = part + pb2[0];
}

extern "C" void kernel_launch(void* const* d_in, const int* in_sizes, int n_in,
                              void* d_out, int out_size, void* d_ws, size_t ws_size,
                              hipStream_t stream) {
    const int*   atoms = (const int*)d_in[0];
    // d_in[1] = pos (unused), d_in[2] = edge_index (unused)
    const int*   batch = (const int*)d_in[3];
    const float* emb   = (const float*)d_in[4];
    const float* w1    = (const float*)d_in[5];
    const float* b1    = (const float*)d_in[6];
    const float* w2    = (const float*)d_in[7];
    const float* b2    = (const float*)d_in[8];
    const float* pw1   = (const float*)d_in[9];
    const float* pb1   = (const float*)d_in[10];
    const float* pw2   = (const float*)d_in[11];
    const float* pb2   = (const float*)d_in[12];
    float* out = (float*)d_out;
    int n = in_sizes[0];

    float* A   = (float*)d_ws;                                   // 100*64 f32 = 25.6 KB
    int*   seg = (int*)((char*)d_ws + VOCAB * 64 * sizeof(float)); // GSEG+1 ints

    k_table<<<dim3(VOCAB / 2), dim3(128), 0, stream>>>(emb, w1, b1, w2, b2, pw1, A);
    k_seg<<<dim3((n + 255) / 256), dim3(256), 0, stream>>>(batch, n, seg);
    k_main<<<dim3(GSEG), dim3(64), 0, stream>>>(atoms, seg, A, pb1, pw2, pb2, out);
}

// Round 2
// 210.353 us; speedup vs baseline: 1.0131x; 1.0131x over previous
//
#include <hip/hip_runtime.h>
#include <hip/hip_bf16.h>

#define VOCAB 100
#define EMBD 128
#define SDIM 16
#define HID 32
#define NLAYER 5
#define GSEG 8192

// Fused prep kernel.
// Blocks [0, segB)         : segment offsets from sorted batch (256 thr).
// Blocks [segB, segB+50)   : A-table, 2 vocab rows per block (128 of 256 thr).
__global__ void k_prep(const int* __restrict__ batch, int n,
                       const float* __restrict__ emb,
                       const float* __restrict__ w1, const float* __restrict__ b1,
                       const float* __restrict__ w2, const float* __restrict__ b2,
                       const float* __restrict__ pw1,
                       int segB,
                       int* __restrict__ seg, float* __restrict__ A) {
    if ((int)blockIdx.x < segB) {
        // ---- segment offsets: seg[g] = first a with batch[a] >= g ----
        int a = (int)blockIdx.x * 256 + (int)threadIdx.x;
        if (a >= n) return;
        if (a == 0) {
            int b0 = batch[0];
            for (int g = 0; g <= b0; ++g) seg[g] = 0;
        } else {
            int bp = batch[a - 1], bc = batch[a];
            if (bp != bc)
                for (int g = bp + 1; g <= bc; ++g) seg[g] = a;
        }
        if (a == n - 1) {
            int bl = batch[n - 1];
            for (int g = bl + 1; g <= GSEG; ++g) seg[g] = n;
        }
    } else {
        // ---- A table: A[v][j] = scale(v) * dot(emb[v], pw1[:,j]) ----
        __shared__ float s_scale[2];
        int t = (int)threadIdx.x;
        int v0 = ((int)blockIdx.x - segB) * 2;
        if (t < 64) {
            int vv = v0 + (t >> 5);   // which of the two vocab rows
            int jj = t & 31;          // hidden unit 0..31
            float e[SDIM];
            #pragma unroll
            for (int k = 0; k < SDIM; ++k) e[k] = emb[vv * EMBD + k];
            float scale = 1.0f;
            for (int l = 0; l < NLAYER; ++l) {
                float d = 0.f;
                #pragma unroll
                for (int k = 0; k < SDIM; ++k)
                    d = fmaf(e[k], w1[l * (SDIM * HID) + k * HID + jj], d);
                float z = fmaf(scale, d, b1[l * HID + jj]);
                z = fmaxf(z, 0.f);
                float p = z * w2[l * HID + jj];
                #pragma unroll
                for (int off = 16; off; off >>= 1)
                    p += __shfl_xor(p, off, 32);     // 32-lane butterfly sum
                float logit = p + b2[l];
                float m = 1.f / (1.f + expf(-logit));
                if (!(m > 0.5f)) scale *= (1.f - m); // m>0.5 => h unchanged
            }
            if (jj == 0) s_scale[t >> 5] = scale;
        }
        __syncthreads();
        if (t < 128) {
            int vl = t >> 6;          // 0..1
            int j  = t & 63;
            int v  = v0 + vl;
            float sc = s_scale[vl];
            float acc = 0.f;
            #pragma unroll 4
            for (int d = 0; d < EMBD; ++d)
                acc = fmaf(emb[v * EMBD + d], pw1[d * 64 + j], acc);
            A[v * 64 + j] = sc * acc;
        }
    }
}

// One 64-thread block per segment: LDS histogram of its atoms, then
// hidden_j = pb1[j] + sum_v cnt[v]*A[v][j]; out = relu(hidden) . pw2 + pb2.
__global__ void __launch_bounds__(64) k_main(const int* __restrict__ atoms,
                                             const int* __restrict__ seg,
                                             const float* __restrict__ A,
                                             const float* __restrict__ pb1,
                                             const float* __restrict__ pw2,
                                             const float* __restrict__ pb2,
                                             float* __restrict__ out) {
    __shared__ int s_cnt[VOCAB];
    int t = (int)threadIdx.x;
    int g = (int)blockIdx.x;
    for (int i = t; i < VOCAB; i += 64) s_cnt[i] = 0;
    __syncthreads();
    int start = seg[g], end = seg[g + 1];
    for (int a = start + t; a < end; a += 64)
        atomicAdd(&s_cnt[atoms[a]], 1);
    __syncthreads();
    float h = pb1[t];
    #pragma unroll 4
    for (int v = 0; v < VOCAB; ++v)
        h = fmaf((float)s_cnt[v], A[v * 64 + t], h);  // s_cnt: LDS broadcast; A: L1-hot
    float part = fmaxf(h, 0.f) * pw2[t];
    #pragma unroll
    for (int off = 32; off; off >>= 1)
        part += __shfl_down(part, off, 64);
    if (t == 0) out[g] = part + pb2[0];
}

extern "C" void kernel_launch(void* const* d_in, const int* in_sizes, int n_in,
                              void* d_out, int out_size, void* d_ws, size_t ws_size,
                              hipStream_t stream) {
    const int*   atoms = (const int*)d_in[0];
    // d_in[1] = pos (unused), d_in[2] = edge_index (unused)
    const int*   batch = (const int*)d_in[3];
    const float* emb   = (const float*)d_in[4];
    const float* w1    = (const float*)d_in[5];
    const float* b1    = (const float*)d_in[6];
    const float* w2    = (const float*)d_in[7];
    const float* b2    = (const float*)d_in[8];
    const float* pw1   = (const float*)d_in[9];
    const float* pb1   = (const float*)d_in[10];
    const float* pw2   = (const float*)d_in[11];
    const float* pb2   = (const float*)d_in[12];
    float* out = (float*)d_out;
    int n = in_sizes[0];

    float* A   = (float*)d_ws;                                     // 100*64 f32
    int*   seg = (int*)((char*)d_ws + VOCAB * 64 * sizeof(float)); // GSEG+1 ints

    int segB = (n + 255) / 256;
    k_prep<<<dim3(segB + VOCAB / 2), dim3(256), 0, stream>>>(
        batch, n, emb, w1, b1, w2, b2, pw1, segB, seg, A);
    k_main<<<dim3(GSEG), dim3(64), 0, stream>>>(atoms, seg, A, pb1, pw2, pb2, out);
}